// Round 1
// baseline (19026.620 us; speedup 1.0000x reference)
//
#include <hip/hip_runtime.h>
#include <hip/hip_bf16.h>

#define BATCH 64
#define TT 128
#define DD 1024
#define HH 1000

// ---------------------------------------------------------------------------
// zero ws states
__global__ void zero_states(float* __restrict__ p, int nf) {
    int i = blockIdx.x * blockDim.x + threadIdx.x;
    if (i < nf) p[i] = 0.f;
}

// ---------------------------------------------------------------------------
// transpose W [K][4000] (gate-major columns) -> Wt [K*1000] float4 (gate minor)
__global__ void transpose_w(const float* __restrict__ W, float* __restrict__ Wt) {
    int n = blockIdx.x * blockDim.x + threadIdx.x;
    int k = blockIdx.y;
    if (n >= HH) return;
    const float* wp = W + (size_t)k * 4 * HH + n;
    float4 v;
    v.x = wp[0];
    v.y = wp[HH];
    v.z = wp[2 * HH];
    v.w = wp[3 * HH];
    ((float4*)Wt)[(size_t)k * HH + n] = v;
}

// ---------------------------------------------------------------------------
// One pipelined LSTM step: layer1(t) and layer2(t-1) in the same launch.
// mode: 0 = both (256 blocks), 1 = layer1 only (128), 2 = layer2 only (128)
// Block decode keeps all 8 batch-tiles of a weight panel on one XCD
// (bid % 8 == panel % 8 under default round-robin XCD assignment).
template <bool TR>
__global__ __launch_bounds__(512) void lstm_step(
    const float* __restrict__ x, int t, int mode,
    const float* __restrict__ W1, const float* __restrict__ U1, const float* __restrict__ b1,
    const float* __restrict__ W2, const float* __restrict__ U2, const float* __restrict__ b2,
    const float* __restrict__ h1_in, float* __restrict__ h1_out, float* __restrict__ c1,
    const float* __restrict__ h2_in, float* __restrict__ h2_out, float* __restrict__ c2)
{
    int bid = blockIdx.x;
    int layer, ntile, btile;
    if (mode == 0) {
        btile = bid >> 5;          // 0..7
        int r = bid & 31;          // panel id
        layer = r >> 4;            // 0..1
        ntile = r & 15;            // 0..15
    } else {
        btile = bid >> 4;          // 0..7
        ntile = bid & 15;
        layer = (mode == 1) ? 0 : 1;
    }

    const int tid = threadIdx.x;
    const int tn = tid & 63;       // n within tile
    const int tb = tid >> 6;       // 0..7 batch within tile
    const int b = btile * 8 + tb;
    const int n = ntile * 64 + tn;
    const bool valid = (n < HH);
    const int nc = valid ? n : (HH - 1);

    const float *A1, *A2, *Wa, *Wb, *bias;
    float *cptr, *hout;
    int K1, s1;
    if (layer == 0) {
        A1 = x + (size_t)t * DD; K1 = DD; s1 = TT * DD;   // x_t, row stride T*D
        A2 = h1_in;                                        // h1(t-1)
        Wa = W1; Wb = U1; bias = b1;
        cptr = c1; hout = h1_out;
    } else {
        A1 = h1_in; K1 = HH; s1 = HH;                      // h1(t-1) for step t-1
        A2 = h2_in;                                        // h2(t-2)
        Wa = W2; Wb = U2; bias = b2;
        cptr = c2; hout = h2_out;
    }

    float4 acc;
    acc.x = bias[0 * HH + nc];
    acc.y = bias[1 * HH + nc];
    acc.z = bias[2 * HH + nc];
    acc.w = bias[3 * HH + nc];

    __shared__ float sA[8][64];

    for (int phase = 0; phase < 2; ++phase) {
        const float* A = phase ? A2 : A1;
        const int K = phase ? HH : K1;
        const int as = phase ? HH : s1;
        const float* W = phase ? Wb : Wa;
        for (int k0 = 0; k0 < K; k0 += 64) {
            int kg = k0 + tn;
            sA[tb][tn] = (kg < K) ? A[(size_t)b * as + kg] : 0.f;
            __syncthreads();
            int kmax = K - k0; if (kmax > 64) kmax = 64;
            if (kmax == 64) {
                #pragma unroll
                for (int kk = 0; kk < 64; ++kk) {
                    float a = sA[tb][kk];
                    float4 w;
                    if (TR) {
                        w = *(const float4*)(W + ((size_t)(k0 + kk) * HH + nc) * 4);
                    } else {
                        const float* wp = W + (size_t)(k0 + kk) * 4 * HH + nc;
                        w.x = wp[0]; w.y = wp[HH]; w.z = wp[2 * HH]; w.w = wp[3 * HH];
                    }
                    acc.x += a * w.x; acc.y += a * w.y;
                    acc.z += a * w.z; acc.w += a * w.w;
                }
            } else {
                for (int kk = 0; kk < kmax; ++kk) {
                    float a = sA[tb][kk];
                    float4 w;
                    if (TR) {
                        w = *(const float4*)(W + ((size_t)(k0 + kk) * HH + nc) * 4);
                    } else {
                        const float* wp = W + (size_t)(k0 + kk) * 4 * HH + nc;
                        w.x = wp[0]; w.y = wp[HH]; w.z = wp[2 * HH]; w.w = wp[3 * HH];
                    }
                    acc.x += a * w.x; acc.y += a * w.y;
                    acc.z += a * w.z; acc.w += a * w.w;
                }
            }
            __syncthreads();
        }
    }

    if (valid) {
        // Keras gate order: i, f, g, o
        float ig = 1.f / (1.f + expf(-acc.x));
        float fg = 1.f / (1.f + expf(-acc.y));
        float gg = tanhf(acc.z);
        float og = 1.f / (1.f + expf(-acc.w));
        size_t idx = (size_t)b * HH + n;
        float c_old = cptr[idx];
        float c_new = fg * c_old + ig * gg;
        cptr[idx] = c_new;
        hout[idx] = og * tanhf(c_new);
    }
}

// ---------------------------------------------------------------------------
// out[b][o] = bo[o] + sum_n h2[b][n] * Wo[n][o]
__global__ void out_proj(const float* __restrict__ h2, const float* __restrict__ Wo,
                         const float* __restrict__ bo, float* __restrict__ out)
{
    int b = blockIdx.x, tid = threadIdx.x;
    float acc[6] = {0, 0, 0, 0, 0, 0};
    for (int n = tid; n < HH; n += 256) {
        float h = h2[(size_t)b * HH + n];
        #pragma unroll
        for (int o = 0; o < 6; ++o) acc[o] += h * Wo[n * 6 + o];
    }
    #pragma unroll
    for (int o = 0; o < 6; ++o)
        for (int off = 32; off; off >>= 1) acc[o] += __shfl_down(acc[o], off, 64);
    __shared__ float red[4][6];
    int lane = tid & 63, wv = tid >> 6;
    if (lane == 0) {
        #pragma unroll
        for (int o = 0; o < 6; ++o) red[wv][o] = acc[o];
    }
    __syncthreads();
    if (tid < 6) {
        float s = bo[tid];
        #pragma unroll
        for (int w = 0; w < 4; ++w) s += red[w][tid];
        out[b * 6 + tid] = s;
    }
}

// ---------------------------------------------------------------------------
extern "C" void kernel_launch(void* const* d_in, const int* in_sizes, int n_in,
                              void* d_out, int out_size, void* d_ws, size_t ws_size,
                              hipStream_t stream) {
    const float* x  = (const float*)d_in[0];
    const float* W1 = (const float*)d_in[1];
    const float* U1 = (const float*)d_in[2];
    const float* b1 = (const float*)d_in[3];
    const float* W2 = (const float*)d_in[4];
    const float* U2 = (const float*)d_in[5];
    const float* b2 = (const float*)d_in[6];
    const float* Wo = (const float*)d_in[7];
    const float* bo = (const float*)d_in[8];
    float* out = (float*)d_out;
    float* ws = (float*)d_ws;

    // ws layout
    float* h1b[2] = { ws, ws + 64000 };
    float* h2b[2] = { ws + 128000, ws + 192000 };
    float* c1 = ws + 256000;
    float* c2 = ws + 320000;
    float* wr1 = ws + 384000;                    // [1024*1000] float4
    float* ur1 = wr1 + (size_t)1024 * 4000;      // [1000*1000] float4
    float* wr2 = ur1 + (size_t)1000 * 4000;
    float* ur2 = wr2 + (size_t)1000 * 4000;
    const size_t need = (size_t)384000 * 4 + ((size_t)1024 * 4000 + 3ull * 1000 * 4000) * 4;
    const bool tr = (ws_size >= need);

    zero_states<<<dim3(1500), dim3(256), 0, stream>>>(ws, 384000);

    if (tr) {
        transpose_w<<<dim3(4, 1024), dim3(256), 0, stream>>>(W1, wr1);
        transpose_w<<<dim3(4, 1000), dim3(256), 0, stream>>>(U1, ur1);
        transpose_w<<<dim3(4, 1000), dim3(256), 0, stream>>>(W2, wr2);
        transpose_w<<<dim3(4, 1000), dim3(256), 0, stream>>>(U2, ur2);
    }
    const float* pw1 = tr ? wr1 : W1;
    const float* pu1 = tr ? ur1 : U1;
    const float* pw2 = tr ? wr2 : W2;
    const float* pu2 = tr ? ur2 : U2;

    for (int t = 0; t <= TT; ++t) {
        int mode = (t == 0) ? 1 : (t == TT) ? 2 : 0;
        int nb = (mode == 0) ? 256 : 128;
        const float* h1_in = h1b[(t + 1) & 1];   // h1(t-1)
        float* h1_out = h1b[t & 1];              // h1(t)
        const float* h2_in = h2b[t & 1];         // h2(t-2)
        float* h2_out = h2b[(t + 1) & 1];        // h2(t-1)
        if (tr)
            lstm_step<true><<<nb, 512, 0, stream>>>(x, t, mode, pw1, pu1, b1, pw2, pu2, b2,
                                                    h1_in, h1_out, c1, h2_in, h2_out, c2);
        else
            lstm_step<false><<<nb, 512, 0, stream>>>(x, t, mode, pw1, pu1, b1, pw2, pu2, b2,
                                                     h1_in, h1_out, c1, h2_in, h2_out, c2);
    }

    // h2(127) lives in h2b[(128+1)&1] = h2b[1]
    out_proj<<<64, 256, 0, stream>>>(h2b[1], Wo, bo, out);
}

// Round 2
// 9065.573 us; speedup vs baseline: 2.0988x; 2.0988x over previous
//
#include <hip/hip_runtime.h>
#include <hip/hip_bf16.h>

#define BATCH 64
#define TT 128
#define DD 1024   // padded per-operand K (x:1024, h:1000->1024)
#define HH 1000
#define NT 250    // 16-wide column tiles over N'=4000 (gate-interleaved)

typedef float f32x4 __attribute__((ext_vector_type(4)));
typedef __bf16 bf16x8 __attribute__((ext_vector_type(8)));
typedef __bf16 bf16x4 __attribute__((ext_vector_type(4)));

// ---------------------------------------------------------------------------
__global__ void zero_ws(unsigned int* __restrict__ p, int nwords) {
    int i = blockIdx.x * blockDim.x + threadIdx.x;
    if (i < nwords) p[i] = 0u;
}

// ---------------------------------------------------------------------------
// split x (64*128*1024 fp32) into bf16 hi + bf16 lo (residual), same layout
__global__ void split_x(const float* __restrict__ x, __bf16* __restrict__ xh,
                        __bf16* __restrict__ xl) {
    int gid = blockIdx.x * blockDim.x + threadIdx.x;   // 2,097,152 threads
    float4 v = ((const float4*)x)[gid];
    float f[4] = {v.x, v.y, v.z, v.w};
    bf16x4 hi, lo;
#pragma unroll
    for (int j = 0; j < 4; ++j) {
        __bf16 h = (__bf16)f[j];
        hi[j] = h;
        lo[j] = (__bf16)(f[j] - (float)h);
    }
    ((bf16x4*)xh)[gid] = hi;
    ((bf16x4*)xl)[gid] = lo;
}

// ---------------------------------------------------------------------------
// Pack W (K x 4000 gate-major) + U into MFMA-B-fragment order, bf16 hi/lo.
// Packed index: ((nt*256 + kb)*16 + col)*8 + j ; col' = 4*cell + gate.
// kb 0..127 = first operand (x/h1, K padded 1024), kb 128..255 = U (1000->1024).
__global__ void pack_w(const float* __restrict__ W1, const float* __restrict__ U1,
                       const float* __restrict__ W2, const float* __restrict__ U2,
                       __bf16* __restrict__ w1h, __bf16* __restrict__ w1l,
                       __bf16* __restrict__ w2h, __bf16* __restrict__ w2l) {
    int layer = blockIdx.y;
    int gid = blockIdx.x * 256 + threadIdx.x;   // grid.x = 4096
    int col = gid & 15;
    int kb = (gid >> 4) & 255;
    int nt = gid >> 12;
    if (nt >= NT) return;
    const float* R1 = layer ? W2 : W1;
    const float* R2 = layer ? U2 : U1;
    int k1v = layer ? HH : 1024;
    __bf16* dh = layer ? w2h : w1h;
    __bf16* dl = layer ? w2l : w1l;
    int cell = nt * 4 + (col >> 2), gate = col & 3;
    size_t gcol = (size_t)gate * HH + cell;
    size_t o = (size_t)gid * 8;
#pragma unroll
    for (int j = 0; j < 8; ++j) {
        int k = kb * 8 + j;
        float v;
        if (k < 1024) v = (k < k1v) ? R1[(size_t)k * 4000 + gcol] : 0.f;
        else { int kk = k - 1024; v = (kk < HH) ? R2[(size_t)kk * 4000 + gcol] : 0.f; }
        __bf16 h = (__bf16)v;
        dh[o + j] = h;
        dl[o + j] = (__bf16)(v - (float)h);
    }
}

// ---------------------------------------------------------------------------
// 1024-K half of the GEMM: acc += split-bf16( A[64 x 1024] @ W[1024 x 16cols] )
__device__ __forceinline__ void gemm_1024(
    const __bf16* __restrict__ Ah, const __bf16* __restrict__ Al,
    size_t abase, int rs,
    const __bf16* __restrict__ Wh, const __bf16* __restrict__ Wl, size_t wbase,
    int lane, f32x4* acc)
{
    int ln = lane & 15, kg = lane >> 4;
    const __bf16* aph[4];
    const __bf16* apl[4];
#pragma unroll
    for (int mt = 0; mt < 4; ++mt) {
        size_t off = abase + (size_t)(mt * 16 + ln) * rs + (size_t)kg * 8;
        aph[mt] = Ah + off;
        apl[mt] = Al + off;
    }
    const __bf16* wh = Wh + wbase;
    const __bf16* wl = Wl + wbase;
#pragma unroll 2
    for (int ks = 0; ks < 32; ++ks) {
        bf16x8 bh = *(const bf16x8*)wh; wh += 512;
        bf16x8 bl = *(const bf16x8*)wl; wl += 512;
#pragma unroll
        for (int mt = 0; mt < 4; ++mt) {
            bf16x8 a_h = *(const bf16x8*)aph[mt]; aph[mt] += 32;
            bf16x8 a_l = *(const bf16x8*)apl[mt]; apl[mt] += 32;
            acc[mt] = __builtin_amdgcn_mfma_f32_16x16x32_bf16(a_h, bh, acc[mt], 0, 0, 0);
            acc[mt] = __builtin_amdgcn_mfma_f32_16x16x32_bf16(a_h, bl, acc[mt], 0, 0, 0);
            acc[mt] = __builtin_amdgcn_mfma_f32_16x16x32_bf16(a_l, bh, acc[mt], 0, 0, 0);
        }
    }
}

// ---------------------------------------------------------------------------
// One pipelined step: layer1(t) and layer2(t-1).
// mode: 0 = both (126 blocks, layer = bid&1), 1 = layer1 only, 2 = layer2 only.
// Block = 4 waves; wave w owns 16 gate-interleaved columns (nt = nb*4+w);
// block covers cells nb*16 .. nb*16+15 for all 64 batch rows.
__global__ __launch_bounds__(256) void lstm_step(
    const __bf16* __restrict__ xh, const __bf16* __restrict__ xl, int t, int mode,
    const __bf16* __restrict__ w1h, const __bf16* __restrict__ w1l,
    const __bf16* __restrict__ w2h, const __bf16* __restrict__ w2l,
    const float* __restrict__ b1, const float* __restrict__ b2,
    const __bf16* __restrict__ h1ih, const __bf16* __restrict__ h1il,
    __bf16* __restrict__ h1oh, __bf16* __restrict__ h1ol, float* __restrict__ c1,
    const __bf16* __restrict__ h2ih, const __bf16* __restrict__ h2il,
    __bf16* __restrict__ h2oh, __bf16* __restrict__ h2ol, float* __restrict__ c2)
{
    int bid = blockIdx.x;
    int layer, nb;
    if (mode == 0) { layer = bid & 1; nb = bid >> 1; }
    else           { layer = (mode == 2); nb = bid; }

    int tid = threadIdx.x, wv = tid >> 6, lane = tid & 63;
    int nt = nb * 4 + wv;
    int ntc = nt < NT ? nt : NT - 1;   // clamp; results masked in epilogue

    const __bf16 *A1h, *A1l, *A2h, *A2l, *Wh, *Wl;
    const float* bias;
    float* cp;
    __bf16 *oh, *ol;
    size_t a1base;
    int rs1;
    if (layer == 0) {
        A1h = xh; A1l = xl; a1base = (size_t)t * DD; rs1 = TT * DD;  // x_t
        A2h = h1ih; A2l = h1il;                                      // h1(t-1)
        Wh = w1h; Wl = w1l; bias = b1; cp = c1; oh = h1oh; ol = h1ol;
    } else {
        A1h = h1ih; A1l = h1il; a1base = 0; rs1 = DD;                // h1(t-1)
        A2h = h2ih; A2l = h2il;                                      // h2(t-2)
        Wh = w2h; Wl = w2l; bias = b2; cp = c2; oh = h2oh; ol = h2ol;
    }

    f32x4 acc[4];
#pragma unroll
    for (int mt = 0; mt < 4; ++mt) acc[mt] = (f32x4){0.f, 0.f, 0.f, 0.f};

    int ln = lane & 15, kg = lane >> 4;
    size_t wbase = (((size_t)ntc * 256 + kg) * 16 + ln) * 8;
    gemm_1024(A1h, A1l, a1base, rs1, Wh, Wl, wbase, lane, acc);
    gemm_1024(A2h, A2l, 0, DD, Wh, Wl, wbase + 128 * 16 * 8, lane, acc);

    // z tile -> LDS (D-frag: col = lane&15, row = (lane>>4)*4 + reg)
    __shared__ float zs[64][68];
#pragma unroll
    for (int mt = 0; mt < 4; ++mt)
#pragma unroll
        for (int r = 0; r < 4; ++r)
            zs[mt * 16 + kg * 4 + r][wv * 16 + ln] = acc[mt][r];
    __syncthreads();

    // fused gates: each thread 4 cells; cols' 4c..4c+3 = (i,f,g,o) for cell c
#pragma unroll
    for (int i = 0; i < 4; ++i) {
        int it = tid + i * 256;
        int b = it >> 4, cl = it & 15;
        int n = nb * 16 + cl;
        if (n < HH) {
            float4 z = *(const float4*)&zs[b][cl * 4];
            float zi = z.x + bias[n];
            float zf = z.y + bias[HH + n];
            float zg = z.z + bias[2 * HH + n];
            float zo = z.w + bias[3 * HH + n];
            float ig = 1.f / (1.f + __expf(-zi));
            float fg = 1.f / (1.f + __expf(-zf));
            float gg = tanhf(zg);
            float og = 1.f / (1.f + __expf(-zo));
            size_t ci = (size_t)b * HH + n;
            float cn = fg * cp[ci] + ig * gg;
            cp[ci] = cn;
            float h = og * tanhf(cn);
            __bf16 hh_ = (__bf16)h;
            size_t hi_ = (size_t)b * DD + n;
            oh[hi_] = hh_;
            ol[hi_] = (__bf16)(h - (float)hh_);
        }
    }
}

// ---------------------------------------------------------------------------
__global__ void out_proj(const __bf16* __restrict__ h2h, const __bf16* __restrict__ h2l,
                         const float* __restrict__ Wo, const float* __restrict__ bo,
                         float* __restrict__ out)
{
    int b = blockIdx.x, tid = threadIdx.x;
    float acc[6] = {0, 0, 0, 0, 0, 0};
    for (int n = tid; n < HH; n += 256) {
        float h = (float)h2h[(size_t)b * DD + n] + (float)h2l[(size_t)b * DD + n];
#pragma unroll
        for (int o = 0; o < 6; ++o) acc[o] += h * Wo[n * 6 + o];
    }
#pragma unroll
    for (int o = 0; o < 6; ++o)
        for (int off = 32; off; off >>= 1) acc[o] += __shfl_down(acc[o], off, 64);
    __shared__ float red[4][6];
    int lane = tid & 63, wv = tid >> 6;
    if (lane == 0) {
#pragma unroll
        for (int o = 0; o < 6; ++o) red[wv][o] = acc[o];
    }
    __syncthreads();
    if (tid < 6) {
        float s = bo[tid];
#pragma unroll
        for (int w = 0; w < 4; ++w) s += red[w][tid];
        out[b * 6 + tid] = s;
    }
}

// ---------------------------------------------------------------------------
extern "C" void kernel_launch(void* const* d_in, const int* in_sizes, int n_in,
                              void* d_out, int out_size, void* d_ws, size_t ws_size,
                              hipStream_t stream) {
    const float* x  = (const float*)d_in[0];
    const float* W1 = (const float*)d_in[1];
    const float* U1 = (const float*)d_in[2];
    const float* b1 = (const float*)d_in[3];
    const float* W2 = (const float*)d_in[4];
    const float* U2 = (const float*)d_in[5];
    const float* b2 = (const float*)d_in[6];
    const float* Wo = (const float*)d_in[7];
    const float* bo = (const float*)d_in[8];
    float* out = (float*)d_out;

    // ws carve (bytes). State region (c + h buffers) first so one zero kernel covers it.
    char* p = (char*)d_ws;
    float* c1 = (float*)p; p += 256000;
    float* c2 = (float*)p; p += 256000;
    __bf16* hbuf = (__bf16*)p; p += (size_t)8 * 65536 * 2;     // 8 x [64][1024]
    __bf16* xh = (__bf16*)p; p += (size_t)8388608 * 2;
    __bf16* xl = (__bf16*)p; p += (size_t)8388608 * 2;
    __bf16* w1h = (__bf16*)p; p += (size_t)8192000 * 2;
    __bf16* w1l = (__bf16*)p; p += (size_t)8192000 * 2;
    __bf16* w2h = (__bf16*)p; p += (size_t)8192000 * 2;
    __bf16* w2l = (__bf16*)p; p += (size_t)8192000 * 2;

    __bf16* h1h[2] = { hbuf + 0 * 65536, hbuf + 1 * 65536 };
    __bf16* h1l[2] = { hbuf + 2 * 65536, hbuf + 3 * 65536 };
    __bf16* h2h[2] = { hbuf + 4 * 65536, hbuf + 5 * 65536 };
    __bf16* h2l[2] = { hbuf + 6 * 65536, hbuf + 7 * 65536 };

    // ---- preprocessing (each launch; deterministic) ----
    zero_ws<<<1525, 256, 0, stream>>>((unsigned int*)d_ws, 390144);
    split_x<<<8192, 256, 0, stream>>>(x, xh, xl);
    pack_w<<<dim3(4096, 2), 256, 0, stream>>>(W1, U1, W2, U2, w1h, w1l, w2h, w2l);

    // ---- 129 pipelined steps ----
    for (int t = 0; t <= TT; ++t) {
        int mode = (t == 0) ? 1 : (t == TT) ? 2 : 0;
        int nb = (mode == 0) ? 126 : 63;
        lstm_step<<<nb, 256, 0, stream>>>(
            xh, xl, t, mode, w1h, w1l, w2h, w2l, b1, b2,
            h1h[(t + 1) & 1], h1l[(t + 1) & 1], h1h[t & 1], h1l[t & 1], c1,
            h2h[t & 1], h2l[t & 1], h2h[(t + 1) & 1], h2l[(t + 1) & 1], c2);
    }

    // h2(127) lives in buffer index 1
    out_proj<<<64, 256, 0, stream>>>(h2h[1], h2l[1], Wo, bo, out);
}

// Round 3
// 2188.021 us; speedup vs baseline: 8.6958x; 4.1433x over previous
//
#include <hip/hip_runtime.h>
#include <hip/hip_bf16.h>

#define BATCH 64
#define TT 128
#define DD 1024   // padded per-operand K
#define HH 1000
#define NT 250    // 16-wide gate-interleaved col tiles over N'=4000

typedef float f32x4 __attribute__((ext_vector_type(4)));
typedef __bf16 bf16x8 __attribute__((ext_vector_type(8)));

// ---------------------------------------------------------------------------
__global__ void zero_ws(unsigned int* __restrict__ p, int nwords) {
    int i = blockIdx.x * blockDim.x + threadIdx.x;
    if (i < nwords) p[i] = 0u;
}

// ---------------------------------------------------------------------------
// split x into bf16 hi/lo, written directly in MFMA A-fragment order:
// unit gid = ((t*32 + ks)*4 + mt)*64 + lane ; lane=(kg<<4)|ln
// element j of unit = x[b = mt*16+ln][t][k = ks*32 + kg*8 + j]
__global__ void split_x(const float* __restrict__ x, __bf16* __restrict__ xfh,
                        __bf16* __restrict__ xfl) {
    int gid = blockIdx.x * 256 + threadIdx.x;     // 1,048,576 units
    int lane = gid & 63;
    int mt = (gid >> 6) & 3;
    int ks = (gid >> 8) & 31;
    int t  = gid >> 13;
    int row = mt * 16 + (lane & 15);
    int k0  = ks * 32 + (lane >> 4) * 8;
    const float* sp = x + ((size_t)row * TT + t) * 1024 + k0;
    float4 v0 = *(const float4*)sp;
    float4 v1 = *(const float4*)(sp + 4);
    float f[8] = {v0.x, v0.y, v0.z, v0.w, v1.x, v1.y, v1.z, v1.w};
    bf16x8 hv, lv;
#pragma unroll
    for (int j = 0; j < 8; ++j) {
        __bf16 h = (__bf16)f[j];
        hv[j] = h;
        lv[j] = (__bf16)(f[j] - (float)h);
    }
    ((bf16x8*)xfh)[gid] = hv;
    ((bf16x8*)xfl)[gid] = lv;
}

// ---------------------------------------------------------------------------
// Pack W/U into MFMA-B-fragment order, bf16 hi/lo (verified layout, round 2).
// unit = (nt*256 + kb)*16 + col ; col' = 4*cell + gate ; kb<128: W, kb>=128: U
__global__ void pack_w(const float* __restrict__ W1, const float* __restrict__ U1,
                       const float* __restrict__ W2, const float* __restrict__ U2,
                       __bf16* __restrict__ w1h, __bf16* __restrict__ w1l,
                       __bf16* __restrict__ w2h, __bf16* __restrict__ w2l) {
    int layer = blockIdx.y;
    int gid = blockIdx.x * 256 + threadIdx.x;
    int col = gid & 15;
    int kb = (gid >> 4) & 255;
    int nt = gid >> 12;
    if (nt >= NT) return;
    const float* R1 = layer ? W2 : W1;
    const float* R2 = layer ? U2 : U1;
    int k1v = layer ? HH : 1024;
    __bf16* dh = layer ? w2h : w1h;
    __bf16* dl = layer ? w2l : w1l;
    int cell = nt * 4 + (col >> 2), gate = col & 3;
    size_t gcol = (size_t)gate * HH + cell;
    size_t o = (size_t)gid * 8;
#pragma unroll
    for (int j = 0; j < 8; ++j) {
        int k = kb * 8 + j;
        float v;
        if (k < 1024) v = (k < k1v) ? R1[(size_t)k * 4000 + gcol] : 0.f;
        else { int kk = k - 1024; v = (kk < HH) ? R2[(size_t)kk * 4000 + gcol] : 0.f; }
        __bf16 h = (__bf16)v;
        dh[o + j] = h;
        dl[o + j] = (__bf16)(v - (float)h);
    }
}

// ---------------------------------------------------------------------------
// Pipelined step: layer1(t) and layer2(t-1).
// mode 0: 250 blocks (layer=bid&1, nb=bid>>1); mode 1/2: 125 blocks single layer.
// Block = 4 waves = 2 col-tiles (nt = nb*2+wv) x 2 operands (op). Covers
// cells nb*8..nb*8+7 for all 64 batch rows. All A/W loads are contiguous
// 1KB coalesced wave-loads from fragment-ordered buffers; depth-4 prefetch.
__global__ __launch_bounds__(256, 1) void lstm_step(
    const __bf16* __restrict__ xfh, const __bf16* __restrict__ xfl, int t, int mode,
    const __bf16* __restrict__ w1h, const __bf16* __restrict__ w1l,
    const __bf16* __restrict__ w2h, const __bf16* __restrict__ w2l,
    const float* __restrict__ b1, const float* __restrict__ b2,
    const __bf16* __restrict__ h1ih, const __bf16* __restrict__ h1il,
    __bf16* __restrict__ h1oh, __bf16* __restrict__ h1ol, float* __restrict__ c1,
    const __bf16* __restrict__ h2ih, const __bf16* __restrict__ h2il,
    __bf16* __restrict__ h2oh, __bf16* __restrict__ h2ol, float* __restrict__ c2)
{
    int bid = blockIdx.x;
    int layer, nb;
    if (mode == 0) { layer = bid & 1; nb = bid >> 1; }
    else           { layer = (mode == 2); nb = bid; }

    int tid = threadIdx.x;
    int lane = tid & 63, w = tid >> 6;
    int wv = w & 1, op = w >> 1;
    int ln = lane & 15, kg = lane >> 4;
    int nt = nb * 2 + wv;

    const __bf16 *Wh, *Wl, *Ah, *Al;
    const float* bias; float* cp; __bf16 *ohh, *ohl;
    size_t abase = 0;
    if (layer == 0) {
        Wh = w1h; Wl = w1l; bias = b1; cp = c1; ohh = h1oh; ohl = h1ol;
        if (op == 0) { Ah = xfh; Al = xfl; abase = (size_t)t * 8192; }
        else         { Ah = h1ih; Al = h1il; }
    } else {
        Wh = w2h; Wl = w2l; bias = b2; cp = c2; ohh = h2oh; ohl = h2ol;
        if (op == 0) { Ah = h1ih; Al = h1il; }
        else         { Ah = h2ih; Al = h2il; }
    }

    const bf16x8* ap_h = (const bf16x8*)Ah + abase + lane;
    const bf16x8* ap_l = (const bf16x8*)Al + abase + lane;
    size_t wbase = (size_t)nt * 4096 + (size_t)op * 2048 + kg * 16 + ln;
    const bf16x8* wp_h = (const bf16x8*)Wh + wbase;
    const bf16x8* wp_l = (const bf16x8*)Wl + wbase;

    f32x4 acc[4];
#pragma unroll
    for (int mt = 0; mt < 4; ++mt) acc[mt] = (f32x4){0.f, 0.f, 0.f, 0.f};

    bf16x8 bhv[4], blv[4], ahv[4][4], alv[4][4];

#define LD(s, k) do { \
    bhv[s] = wp_h[(k) * 64]; blv[s] = wp_l[(k) * 64]; \
    _Pragma("unroll") \
    for (int mt = 0; mt < 4; ++mt) { \
        ahv[s][mt] = ap_h[(k) * 256 + mt * 64]; \
        alv[s][mt] = ap_l[(k) * 256 + mt * 64]; \
    } } while (0)

#define CP(s) do { \
    _Pragma("unroll") \
    for (int mt = 0; mt < 4; ++mt) \
        acc[mt] = __builtin_amdgcn_mfma_f32_16x16x32_bf16(ahv[s][mt], bhv[s], acc[mt], 0, 0, 0); \
    _Pragma("unroll") \
    for (int mt = 0; mt < 4; ++mt) \
        acc[mt] = __builtin_amdgcn_mfma_f32_16x16x32_bf16(ahv[s][mt], blv[s], acc[mt], 0, 0, 0); \
    _Pragma("unroll") \
    for (int mt = 0; mt < 4; ++mt) \
        acc[mt] = __builtin_amdgcn_mfma_f32_16x16x32_bf16(alv[s][mt], bhv[s], acc[mt], 0, 0, 0); \
    } while (0)

    LD(0, 0); LD(1, 1); LD(2, 2); LD(3, 3);
#pragma unroll 4
    for (int ks = 0; ks < 28; ++ks) {
        int s = ks & 3;
        CP(s);
        LD(s, ks + 4);
    }
#pragma unroll
    for (int ks = 28; ks < 32; ++ks) CP(ks & 3);

#undef LD
#undef CP

    // ---- reduce the two operand halves in LDS, fold bias in ----
    __shared__ float zs[64][36];
    __shared__ float hs[64][9];
    int col = wv * 16 + ln;                       // 0..31 within block
    float bias_v = bias[(size_t)(col & 3) * HH + nb * 8 + (col >> 2)];
    if (op == 0) {
#pragma unroll
        for (int mt = 0; mt < 4; ++mt)
#pragma unroll
            for (int r = 0; r < 4; ++r)
                zs[mt * 16 + kg * 4 + r][col] = acc[mt][r] + bias_v;
    }
    __syncthreads();
    if (op == 1) {
#pragma unroll
        for (int mt = 0; mt < 4; ++mt)
#pragma unroll
            for (int r = 0; r < 4; ++r)
                zs[mt * 16 + kg * 4 + r][col] += acc[mt][r];
    }
    __syncthreads();

    // ---- fused gates: 512 (b, cell) tasks, 2 per thread ----
#pragma unroll
    for (int q = 0; q < 2; ++q) {
        int task = tid * 2 + q;
        int b = task >> 3, cl = task & 7;
        int n = nb * 8 + cl;
        float4 z = *(const float4*)&zs[b][cl * 4];
        float ig = 1.f / (1.f + __expf(-z.x));
        float fg = 1.f / (1.f + __expf(-z.y));
        float gg = 1.f - 2.f / (__expf(2.f * z.z) + 1.f);
        float og = 1.f / (1.f + __expf(-z.w));
        size_t ci = (size_t)b * HH + n;
        float cn = fg * cp[ci] + ig * gg;
        cp[ci] = cn;
        hs[b][cl] = og * (1.f - 2.f / (__expf(2.f * cn) + 1.f));
    }
    __syncthreads();

    // ---- write h in fragment order: 64 threads, one bf16x8 hi+lo each ----
    if (tid < 64) {
        int b = tid;
        int mt = b >> 4, lnn = b & 15;
        int ks = nb >> 2, kgg = nb & 3;
        bf16x8 hv, lv;
#pragma unroll
        for (int j = 0; j < 8; ++j) {
            float v = hs[b][j];
            __bf16 h = (__bf16)v;
            hv[j] = h;
            lv[j] = (__bf16)(v - (float)h);
        }
        size_t unit = ((size_t)ks * 4 + mt) * 64 + kgg * 16 + lnn;
        ((bf16x8*)ohh)[unit] = hv;
        ((bf16x8*)ohl)[unit] = lv;
    }
}

// ---------------------------------------------------------------------------
// out[b][o] = bo[o] + sum_n h2[b][n] * Wo[n][o] ; h2 is in fragment order
__global__ void out_proj(const __bf16* __restrict__ h2h, const __bf16* __restrict__ h2l,
                         const float* __restrict__ Wo, const float* __restrict__ bo,
                         float* __restrict__ out)
{
    int b = blockIdx.x, tid = threadIdx.x;
    int mt = b >> 4, ln = b & 15;
    float acc[6] = {0, 0, 0, 0, 0, 0};
    for (int n = tid; n < HH; n += 256) {
        int ks = n >> 5, kg = (n >> 3) & 3, j = n & 7;
        size_t idx = (((size_t)ks * 4 + mt) * 64 + kg * 16 + ln) * 8 + j;
        float h = (float)h2h[idx] + (float)h2l[idx];
#pragma unroll
        for (int o = 0; o < 6; ++o) acc[o] += h * Wo[n * 6 + o];
    }
#pragma unroll
    for (int o = 0; o < 6; ++o)
        for (int off = 32; off; off >>= 1) acc[o] += __shfl_down(acc[o], off, 64);
    __shared__ float red[4][6];
    int lane = tid & 63, wv = tid >> 6;
    if (lane == 0) {
#pragma unroll
        for (int o = 0; o < 6; ++o) red[wv][o] = acc[o];
    }
    __syncthreads();
    if (tid < 6) {
        float s = bo[tid];
#pragma unroll
        for (int w = 0; w < 4; ++w) s += red[w][tid];
        out[b * 6 + tid] = s;
    }
}

// ---------------------------------------------------------------------------
extern "C" void kernel_launch(void* const* d_in, const int* in_sizes, int n_in,
                              void* d_out, int out_size, void* d_ws, size_t ws_size,
                              hipStream_t stream) {
    const float* x  = (const float*)d_in[0];
    const float* W1 = (const float*)d_in[1];
    const float* U1 = (const float*)d_in[2];
    const float* b1 = (const float*)d_in[3];
    const float* W2 = (const float*)d_in[4];
    const float* U2 = (const float*)d_in[5];
    const float* b2 = (const float*)d_in[6];
    const float* Wo = (const float*)d_in[7];
    const float* bo = (const float*)d_in[8];
    float* out = (float*)d_out;

    // ws carve: states first (one zero kernel covers c1,c2,h frags)
    char* p = (char*)d_ws;
    float* c1 = (float*)p; p += 256000;
    float* c2 = (float*)p; p += 256000;
    __bf16* hbuf = (__bf16*)p; p += (size_t)8 * 65536 * 2;     // 8 x frag[64x1024]
    __bf16* xfh = (__bf16*)p; p += (size_t)8388608 * 2;
    __bf16* xfl = (__bf16*)p; p += (size_t)8388608 * 2;
    __bf16* w1h = (__bf16*)p; p += (size_t)8192000 * 2;
    __bf16* w1l = (__bf16*)p; p += (size_t)8192000 * 2;
    __bf16* w2h = (__bf16*)p; p += (size_t)8192000 * 2;
    __bf16* w2l = (__bf16*)p; p += (size_t)8192000 * 2;

    __bf16* h1h[2] = { hbuf + 0 * 65536, hbuf + 1 * 65536 };
    __bf16* h1l[2] = { hbuf + 2 * 65536, hbuf + 3 * 65536 };
    __bf16* h2h[2] = { hbuf + 4 * 65536, hbuf + 5 * 65536 };
    __bf16* h2l[2] = { hbuf + 6 * 65536, hbuf + 7 * 65536 };

    // ---- preprocessing ----
    zero_ws<<<1525, 256, 0, stream>>>((unsigned int*)d_ws, 390144);
    split_x<<<4096, 256, 0, stream>>>(x, xfh, xfl);
    pack_w<<<dim3(4096, 2), 256, 0, stream>>>(W1, U1, W2, U2, w1h, w1l, w2h, w2l);

    // ---- 129 pipelined steps ----
    for (int t = 0; t <= TT; ++t) {
        int mode = (t == 0) ? 1 : (t == TT) ? 2 : 0;
        int nbk = (mode == 0) ? 250 : 125;
        lstm_step<<<nbk, 256, 0, stream>>>(
            xfh, xfl, t, mode, w1h, w1l, w2h, w2l, b1, b2,
            h1h[(t + 1) & 1], h1l[(t + 1) & 1], h1h[t & 1], h1l[t & 1], c1,
            h2h[t & 1], h2l[t & 1], h2h[(t + 1) & 1], h2l[(t + 1) & 1], c2);
    }

    // h2(127) is in buffer index 1
    out_proj<<<64, 256, 0, stream>>>(h2h[1], h2l[1], Wo, bo, out);
}